// Round 5
// baseline (186.605 us; speedup 1.0000x reference)
//
#include <hip/hip_runtime.h>
#include <hip/hip_bf16.h>

// HeteroLinear fused forward on gfx950: out[i] = x[i] @ W[tv[i]] + b[tv[i]]
// N=131072, IN=OUT=256, T=8, tv sorted. Memory-bound: floor ~268 MB -> ~43 us.
// R5: one wave = one 16x256 output strip, fully register-resident.
//  - all 16 x-loads (16 KB) issued before any dependent op -> deep MLP
//  - x converted once to 8 bf16 A-frags (32 VGPR), reused for all 128 MFMAs
//  - swapped-operand MFMA (mfma(W-frag, x-frag)): lane holds 4 consecutive
//    out-cols of ONE row -> f32x4 stores, per-lane row predicate
//  - B-frags from L2-resident wT (1 MiB), 16 independent acc chains
//  - no LDS, no barriers; __launch_bounds__(256,3) caps VGPR at 168

#define NROWS 131072
#define KD 256
#define ND 256
#define SR 16                      // rows per strip (one wave)
#define NSTRIP (NROWS / SR)        // 8192
#define GRID (NSTRIP / 4)          // 2048 blocks x 4 waves

typedef __attribute__((ext_vector_type(8))) short short8;
typedef __attribute__((ext_vector_type(4))) float f32x4;
typedef __attribute__((ext_vector_type(4))) float flt4;

__device__ inline unsigned short f2bf(float f) {
    unsigned int u = __float_as_uint(f);
    u += 0x7FFFu + ((u >> 16) & 1u);   // RNE
    return (unsigned short)(u >> 16);
}

// ---- weight prep: wT[t][n][k] = bf16(w[t][k][n]) ----
__global__ __launch_bounds__(256) void prep_weights(const float* __restrict__ w,
                                                    unsigned short* __restrict__ wT) {
    __shared__ unsigned short L[8][264];
    const int t  = blockIdx.x >> 5;
    const int k0 = (blockIdx.x & 31) * 8;
    const int tid = threadIdx.x;

    #pragma unroll
    for (int i = 0; i < 2; ++i) {
        int idx = i * 256 + tid;
        int kr  = idx >> 6;
        int nq  = idx & 63;
        const flt4* src = (const flt4*)(w + ((size_t)t * 256 + k0 + kr) * 256);
        flt4 v = src[nq];
        #pragma unroll
        for (int j = 0; j < 4; ++j) L[kr][nq * 4 + j] = f2bf(v[j]);
    }
    __syncthreads();

    int n = tid;
    short8 v;
    #pragma unroll
    for (int j = 0; j < 8; ++j) v[j] = (short)L[j][n];
    *(short8*)(wT + ((size_t)t * 256 + n) * 256 + k0) = v;
}

// ---- main GEMM: register-resident strips, no LDS, no barriers ----
__global__ __launch_bounds__(256, 3) void hetero_gemm(
        const float* __restrict__ x, const int* __restrict__ tv,
        const unsigned short* __restrict__ wT, const float* __restrict__ bias,
        float* __restrict__ out) {
    const int tid  = threadIdx.x;
    const int lane = tid & 63;
    const int wv   = tid >> 6;
    const int cl   = lane & 15;          // strip row index (and D-col)
    const int kg   = lane >> 4;          // k-group / out-col quad
    const int r0   = (blockIdx.x * 4 + wv) * SR;

    // per-lane row type; strip min/max via shuffle (rows 0..15 live in lanes 0..15)
    const int tyl  = tv[r0 + cl];
    const int tmin = __shfl(tyl, 0);
    const int tmax = __shfl(tyl, 15);

    // ---- issue ALL x-loads for the strip up front (16 KB in flight) ----
    const float* xrow = x + (size_t)(r0 + cl) * KD + kg * 8;
    f32x4 xv[16];
    #pragma unroll
    for (int ks = 0; ks < 8; ++ks) {
        xv[2 * ks]     = *(const f32x4*)(xrow + ks * 32);
        xv[2 * ks + 1] = *(const f32x4*)(xrow + ks * 32 + 4);
    }
    // convert once; A-frags live in 32 VGPRs for the whole kernel
    short8 a[8];
    #pragma unroll
    for (int ks = 0; ks < 8; ++ks) {
        #pragma unroll
        for (int j = 0; j < 4; ++j) {
            a[ks][j]     = (short)f2bf(xv[2 * ks][j]);
            a[ks][4 + j] = (short)f2bf(xv[2 * ks + 1][j]);
        }
    }

    for (int t = tmin; t <= tmax; ++t) {
        const unsigned short* Bt = wT + (size_t)t * (KD * ND);

        f32x4 zero = {0.f, 0.f, 0.f, 0.f};
        f32x4 acc[16];
        #pragma unroll
        for (int n = 0; n < 16; ++n) acc[n] = zero;

        #pragma unroll
        for (int ks = 0; ks < 8; ++ks) {
            #pragma unroll
            for (int n = 0; n < 16; ++n) {
                // W-frag: lane cl -> out-col group n*16+cl, k-slice kg*8
                short8 b = *(const short8*)(Bt + (size_t)(n * 16 + cl) * KD
                                            + ks * 32 + kg * 8);
                // swapped operands: D[c][r], c from regs, r = cl
                acc[n] = __builtin_amdgcn_mfma_f32_16x16x32_bf16(b, a[ks], acc[n], 0, 0, 0);
            }
        }

        // epilogue: lane owns row r0+cl, cols n*16 + kg*4 .. +4 -> f32x4 stores
        if (tyl == t) {
            float* orow = out + (size_t)(r0 + cl) * ND + kg * 4;
            #pragma unroll
            for (int n = 0; n < 16; ++n) {
                f32x4 bv = *(const f32x4*)(bias + (size_t)t * ND + n * 16 + kg * 4);
                f32x4 o = acc[n] + bv;
                __builtin_nontemporal_store(o, (f32x4*)(orow + n * 16));
            }
        }
    }
}

extern "C" void kernel_launch(void* const* d_in, const int* in_sizes, int n_in,
                              void* d_out, int out_size, void* d_ws, size_t ws_size,
                              hipStream_t stream) {
    const float* x    = (const float*)d_in[0];
    const int*   tv   = (const int*)d_in[1];
    const float* w    = (const float*)d_in[2];
    const float* bias = (const float*)d_in[3];
    float* out = (float*)d_out;
    unsigned short* wT = (unsigned short*)d_ws;   // 8*256*256*2 = 1 MiB

    prep_weights<<<dim3(256), dim3(256), 0, stream>>>(w, wT);
    hetero_gemm<<<dim3(GRID), dim3(256), 0, stream>>>(x, tv, wT, bias, out);
}

// Round 6
// 87.608 us; speedup vs baseline: 2.1300x; 2.1300x over previous
//
#include <hip/hip_runtime.h>
#include <hip/hip_bf16.h>

// HeteroLinear fused forward on gfx950: out[i] = x[i] @ W[tv[i]] + b[tv[i]]
// N=131072, IN=OUT=256, T=8, tv sorted. HBM floor ~256 MB -> ~41 us.
// R6: kill the B-stream. Block = 256 rows x 256 cols, 8 waves; whole W[t]
// (128 KB bf16) staged to LDS once per block (global_load_lds, source-side
// XOR swizzle), reused by 8 waves x 32 rows. Compute phase does ONLY
// coalesced x-loads (the HBM stream) + swizzled ds_reads + MFMA, no
// barriers. Swapped-operand MFMA -> f32x4 epilogue stores, per-row predicate.

#define NROWS 131072
#define KD 256
#define ND 256
#define BM 256                      // rows per block
#define NBLK (NROWS / BM)           // 512

typedef __attribute__((ext_vector_type(8))) short short8;
typedef __attribute__((ext_vector_type(4))) float f32x4;
typedef __attribute__((ext_vector_type(4))) float flt4;

typedef __attribute__((address_space(3))) unsigned int lds_u32_t;
typedef __attribute__((address_space(1))) unsigned int glb_u32_t;

__device__ inline unsigned short f2bf(float f) {
    unsigned int u = __float_as_uint(f);
    u += 0x7FFFu + ((u >> 16) & 1u);   // RNE
    return (unsigned short)(u >> 16);
}

// ---- weight prep: wT[t][n][k] = bf16(w[t][k][n]) ----
__global__ __launch_bounds__(256) void prep_weights(const float* __restrict__ w,
                                                    unsigned short* __restrict__ wT) {
    __shared__ unsigned short L[8][264];
    const int t  = blockIdx.x >> 5;
    const int k0 = (blockIdx.x & 31) * 8;
    const int tid = threadIdx.x;

    #pragma unroll
    for (int i = 0; i < 2; ++i) {
        int idx = i * 256 + tid;
        int kr  = idx >> 6;
        int nq  = idx & 63;
        const flt4* src = (const flt4*)(w + ((size_t)t * 256 + k0 + kr) * 256);
        flt4 v = src[nq];
        #pragma unroll
        for (int j = 0; j < 4; ++j) L[kr][nq * 4 + j] = f2bf(v[j]);
    }
    __syncthreads();

    int n = tid;
    short8 v;
    #pragma unroll
    for (int j = 0; j < 8; ++j) v[j] = (short)L[j][n];
    *(short8*)(wT + ((size_t)t * 256 + n) * 256 + k0) = v;
}

// ---- main GEMM ----
__global__ __launch_bounds__(512, 2) void hetero_gemm(
        const float* __restrict__ x, const int* __restrict__ tv,
        const unsigned short* __restrict__ wT, const float* __restrict__ bias,
        float* __restrict__ out) {
    // W[t] tile, bf16, [col][k], 512 B per col-row, XOR-swizzled 16B chunks:
    // LDS chunk c of col holds global k-chunk c ^ (col&7).
    __shared__ short Bs[BM * KD];            // 128 KiB

    const int tid  = threadIdx.x;
    const int lane = tid & 63;
    const int wv   = tid >> 6;               // 8 waves
    const int cl   = lane & 15;
    const int kg   = lane >> 4;
    const int r0   = blockIdx.x * BM;
    const int rw   = r0 + wv * 32;           // wave's 32-row strip

    const int tmin = tv[r0];
    const int tmax = tv[r0 + BM - 1];
    const int ty0  = tv[rw + cl];            // type of row (m=0)
    const int ty1  = tv[rw + 16 + cl];       // type of row (m=1)

    for (int t = tmin; t <= tmax; ++t) {
        if (t > tmin) __syncthreads();       // prev-pass reads done before overwrite

        // ---- stage W[t] -> LDS: 8192 16B chunks, 16 wave-rounds ----
        {
            const unsigned short* Wt = wT + (size_t)t * (KD * ND);
            #pragma unroll
            for (int rnd = 0; rnd < 16; ++rnd) {
                int i   = rnd * 512 + tid;   // chunk index 0..8191 (per-lane)
                int col = i >> 5;
                int c   = i & 31;
                int sc  = c ^ (col & 7);     // source-side swizzle
                const unsigned short* gp = Wt + col * KD + sc * 8;
                __builtin_amdgcn_global_load_lds(
                    (const glb_u32_t*)gp,
                    (lds_u32_t*)((char*)Bs + (size_t)(rnd * 512 + wv * 64) * 16),
                    16, 0, 0);
            }
        }
        __syncthreads();                     // drain DMA; tile ready

        // ---- compute: 32 rows x 256 cols per wave, no barriers ----
        f32x4 zero = {0.f, 0.f, 0.f, 0.f};
        f32x4 acc[2][16];
        #pragma unroll
        for (int m = 0; m < 2; ++m)
            #pragma unroll
            for (int n = 0; n < 16; ++n) acc[m][n] = zero;

        short8 a_cur[2], a_nxt[2];
        #pragma unroll
        for (int m = 0; m < 2; ++m) {        // preload ks=0
            const float* ap = x + (size_t)(rw + m * 16 + cl) * KD + kg * 8;
            f32x4 v0 = *(const f32x4*)ap;
            f32x4 v1 = *(const f32x4*)(ap + 4);
            #pragma unroll
            for (int j = 0; j < 4; ++j) {
                a_cur[m][j]     = (short)__bfloat16_as_ushort(__float2bfloat16(v0[j]));
                a_cur[m][4 + j] = (short)__bfloat16_as_ushort(__float2bfloat16(v1[j]));
            }
        }

        const int s = cl & 7;                // swizzle key (col&7 == cl&7)
        #pragma unroll
        for (int ks = 0; ks < 8; ++ks) {
            if (ks < 7) {                    // prefetch next k-slice of x
                #pragma unroll
                for (int m = 0; m < 2; ++m) {
                    const float* ap = x + (size_t)(rw + m * 16 + cl) * KD
                                        + (ks + 1) * 32 + kg * 8;
                    f32x4 v0 = *(const f32x4*)ap;
                    f32x4 v1 = *(const f32x4*)(ap + 4);
                    #pragma unroll
                    for (int j = 0; j < 4; ++j) {
                        a_nxt[m][j]     = (short)__bfloat16_as_ushort(__float2bfloat16(v0[j]));
                        a_nxt[m][4 + j] = (short)__bfloat16_as_ushort(__float2bfloat16(v1[j]));
                    }
                }
            }
            #pragma unroll
            for (int n = 0; n < 16; ++n) {
                int col = n * 16 + cl;
                int kc  = ((ks << 2) | kg) ^ s;           // swizzled 16B chunk
                short8 b = *(const short8*)((char*)Bs + (size_t)col * 512 + (kc << 4));
                // swapped operands: D[w-col][x-row]
                acc[0][n] = __builtin_amdgcn_mfma_f32_16x16x32_bf16(b, a_cur[0], acc[0][n], 0, 0, 0);
                acc[1][n] = __builtin_amdgcn_mfma_f32_16x16x32_bf16(b, a_cur[1], acc[1][n], 0, 0, 0);
            }
            a_cur[0] = a_nxt[0];
            a_cur[1] = a_nxt[1];
        }

        // ---- epilogue: lane owns rows rw+m*16+cl, cols n*16+kg*4..+3 ----
        #pragma unroll
        for (int m = 0; m < 2; ++m) {
            int tym = (m == 0) ? ty0 : ty1;
            if (tym == t) {
                float* orow = out + (size_t)(rw + m * 16 + cl) * ND + kg * 4;
                #pragma unroll
                for (int n = 0; n < 16; ++n) {
                    f32x4 bv = *(const f32x4*)(bias + (size_t)t * ND + n * 16 + kg * 4);
                    f32x4 o  = acc[m][n] + bv;
                    __builtin_nontemporal_store(o, (f32x4*)(orow + n * 16));
                }
            }
        }
    }
}

extern "C" void kernel_launch(void* const* d_in, const int* in_sizes, int n_in,
                              void* d_out, int out_size, void* d_ws, size_t ws_size,
                              hipStream_t stream) {
    const float* x    = (const float*)d_in[0];
    const int*   tv   = (const int*)d_in[1];
    const float* w    = (const float*)d_in[2];
    const float* bias = (const float*)d_in[3];
    float* out = (float*)d_out;
    unsigned short* wT = (unsigned short*)d_ws;   // 8*256*256*2 = 1 MiB

    prep_weights<<<dim3(256), dim3(256), 0, stream>>>(w, wT);
    hetero_gemm<<<dim3(NBLK), dim3(512), 0, stream>>>(x, tv, wT, bias, out);
}

// Round 7
// 85.603 us; speedup vs baseline: 2.1799x; 1.0234x over previous
//
#include <hip/hip_runtime.h>
#include <hip/hip_bf16.h>

// HeteroLinear fused forward on gfx950: out[i] = x[i] @ W[tv[i]] + b[tv[i]]
// N=131072, IN=OUT=256, T=8, tv sorted. HBM floor ~256 MB -> ~41 us.
// R7 = R6 with ONE change: __launch_bounds__(512,1) instead of (512,2).
// R6's (512,2) capped VGPR at 128 while acc alone needs 128 -> spill
// (WRITE 170 MB vs 131 ideal). LDS=128KB caps at 1 block/CU anyway, so the
// 2-block request bought nothing and cost everything. With the cap lifted
// (~190 VGPR live), compute phase runs from registers; binding resource
// should become the x/out HBM stream.

#define NROWS 131072
#define KD 256
#define ND 256
#define BM 256                      // rows per block
#define NBLK (NROWS / BM)           // 512

typedef __attribute__((ext_vector_type(8))) short short8;
typedef __attribute__((ext_vector_type(4))) float f32x4;
typedef __attribute__((ext_vector_type(4))) float flt4;

typedef __attribute__((address_space(3))) unsigned int lds_u32_t;
typedef __attribute__((address_space(1))) unsigned int glb_u32_t;

__device__ inline unsigned short f2bf(float f) {
    unsigned int u = __float_as_uint(f);
    u += 0x7FFFu + ((u >> 16) & 1u);   // RNE
    return (unsigned short)(u >> 16);
}

// ---- weight prep: wT[t][n][k] = bf16(w[t][k][n]) ----
__global__ __launch_bounds__(256) void prep_weights(const float* __restrict__ w,
                                                    unsigned short* __restrict__ wT) {
    __shared__ unsigned short L[8][264];
    const int t  = blockIdx.x >> 5;
    const int k0 = (blockIdx.x & 31) * 8;
    const int tid = threadIdx.x;

    #pragma unroll
    for (int i = 0; i < 2; ++i) {
        int idx = i * 256 + tid;
        int kr  = idx >> 6;
        int nq  = idx & 63;
        const flt4* src = (const flt4*)(w + ((size_t)t * 256 + k0 + kr) * 256);
        flt4 v = src[nq];
        #pragma unroll
        for (int j = 0; j < 4; ++j) L[kr][nq * 4 + j] = f2bf(v[j]);
    }
    __syncthreads();

    int n = tid;
    short8 v;
    #pragma unroll
    for (int j = 0; j < 8; ++j) v[j] = (short)L[j][n];
    *(short8*)(wT + ((size_t)t * 256 + n) * 256 + k0) = v;
}

// ---- main GEMM ----
__global__ __launch_bounds__(512, 1) void hetero_gemm(
        const float* __restrict__ x, const int* __restrict__ tv,
        const unsigned short* __restrict__ wT, const float* __restrict__ bias,
        float* __restrict__ out) {
    // W[t] tile, bf16, [col][k], 512 B per col-row, XOR-swizzled 16B chunks:
    // LDS chunk c of col holds global k-chunk c ^ (col&7).
    __shared__ short Bs[BM * KD];            // 128 KiB

    const int tid  = threadIdx.x;
    const int lane = tid & 63;
    const int wv   = tid >> 6;               // 8 waves
    const int cl   = lane & 15;
    const int kg   = lane >> 4;
    const int r0   = blockIdx.x * BM;
    const int rw   = r0 + wv * 32;           // wave's 32-row strip

    const int tmin = tv[r0];
    const int tmax = tv[r0 + BM - 1];
    const int ty0  = tv[rw + cl];            // type of row (m=0)
    const int ty1  = tv[rw + 16 + cl];       // type of row (m=1)

    for (int t = tmin; t <= tmax; ++t) {
        if (t > tmin) __syncthreads();       // prev-pass reads done before overwrite

        // ---- stage W[t] -> LDS: 8192 16B chunks, 16 wave-rounds ----
        {
            const unsigned short* Wt = wT + (size_t)t * (KD * ND);
            #pragma unroll
            for (int rnd = 0; rnd < 16; ++rnd) {
                int i   = rnd * 512 + tid;   // chunk index 0..8191 (per-lane)
                int col = i >> 5;
                int c   = i & 31;
                int sc  = c ^ (col & 7);     // source-side swizzle
                const unsigned short* gp = Wt + col * KD + sc * 8;
                __builtin_amdgcn_global_load_lds(
                    (const glb_u32_t*)gp,
                    (lds_u32_t*)((char*)Bs + (size_t)(rnd * 512 + wv * 64) * 16),
                    16, 0, 0);
            }
        }
        __syncthreads();                     // drain DMA; tile ready

        // ---- compute: 32 rows x 256 cols per wave, no barriers ----
        f32x4 zero = {0.f, 0.f, 0.f, 0.f};
        f32x4 acc[2][16];
        #pragma unroll
        for (int m = 0; m < 2; ++m)
            #pragma unroll
            for (int n = 0; n < 16; ++n) acc[m][n] = zero;

        short8 a_cur[2], a_nxt[2];
        #pragma unroll
        for (int m = 0; m < 2; ++m) {        // preload ks=0
            const float* ap = x + (size_t)(rw + m * 16 + cl) * KD + kg * 8;
            f32x4 v0 = *(const f32x4*)ap;
            f32x4 v1 = *(const f32x4*)(ap + 4);
            #pragma unroll
            for (int j = 0; j < 4; ++j) {
                a_cur[m][j]     = (short)__bfloat16_as_ushort(__float2bfloat16(v0[j]));
                a_cur[m][4 + j] = (short)__bfloat16_as_ushort(__float2bfloat16(v1[j]));
            }
        }

        const int s = cl & 7;                // swizzle key (col&7 == cl&7)
        #pragma unroll
        for (int ks = 0; ks < 8; ++ks) {
            if (ks < 7) {                    // prefetch next k-slice of x
                #pragma unroll
                for (int m = 0; m < 2; ++m) {
                    const float* ap = x + (size_t)(rw + m * 16 + cl) * KD
                                        + (ks + 1) * 32 + kg * 8;
                    f32x4 v0 = *(const f32x4*)ap;
                    f32x4 v1 = *(const f32x4*)(ap + 4);
                    #pragma unroll
                    for (int j = 0; j < 4; ++j) {
                        a_nxt[m][j]     = (short)__bfloat16_as_ushort(__float2bfloat16(v0[j]));
                        a_nxt[m][4 + j] = (short)__bfloat16_as_ushort(__float2bfloat16(v1[j]));
                    }
                }
            }
            #pragma unroll
            for (int n = 0; n < 16; ++n) {
                int col = n * 16 + cl;
                int kc  = ((ks << 2) | kg) ^ s;           // swizzled 16B chunk
                short8 b = *(const short8*)((char*)Bs + (size_t)col * 512 + (kc << 4));
                // swapped operands: D[w-col][x-row]
                acc[0][n] = __builtin_amdgcn_mfma_f32_16x16x32_bf16(b, a_cur[0], acc[0][n], 0, 0, 0);
                acc[1][n] = __builtin_amdgcn_mfma_f32_16x16x32_bf16(b, a_cur[1], acc[1][n], 0, 0, 0);
            }
            a_cur[0] = a_nxt[0];
            a_cur[1] = a_nxt[1];
        }

        // ---- epilogue: lane owns rows rw+m*16+cl, cols n*16+kg*4..+3 ----
        #pragma unroll
        for (int m = 0; m < 2; ++m) {
            int tym = (m == 0) ? ty0 : ty1;
            if (tym == t) {
                float* orow = out + (size_t)(rw + m * 16 + cl) * ND + kg * 4;
                #pragma unroll
                for (int n = 0; n < 16; ++n) {
                    f32x4 bv = *(const f32x4*)(bias + (size_t)t * ND + n * 16 + kg * 4);
                    f32x4 o  = acc[m][n] + bv;
                    __builtin_nontemporal_store(o, (f32x4*)(orow + n * 16));
                }
            }
        }
    }
}

extern "C" void kernel_launch(void* const* d_in, const int* in_sizes, int n_in,
                              void* d_out, int out_size, void* d_ws, size_t ws_size,
                              hipStream_t stream) {
    const float* x    = (const float*)d_in[0];
    const int*   tv   = (const int*)d_in[1];
    const float* w    = (const float*)d_in[2];
    const float* bias = (const float*)d_in[3];
    float* out = (float*)d_out;
    unsigned short* wT = (unsigned short*)d_ws;   // 8*256*256*2 = 1 MiB

    prep_weights<<<dim3(256), dim3(256), 0, stream>>>(w, wT);
    hetero_gemm<<<dim3(NBLK), dim3(512), 0, stream>>>(x, tv, wT, bias, out);
}

// Round 8
// 72.266 us; speedup vs baseline: 2.5822x; 1.1846x over previous
//
#include <hip/hip_runtime.h>
#include <hip/hip_bf16.h>

// HeteroLinear fused forward on gfx950: out[i] = x[i] @ W[tv[i]] + b[tv[i]]
// N=131072, IN=OUT=256, T=8, tv sorted. HBM floor ~256 MB -> ~41 us.
// R8: R7 structure, but accumulator state halved to fit the HARD 128-VGPR
// cap (512-thread block => 8 waves co-resident => >=2 waves/EU => cap 128;
// R2/R5/R6/R7 all spilled, visible as WRITE 161-170 MB vs 131 ideal).
// Wave computes its 32 rows x 256 cols in TWO sequential col-halves of 128:
// acc[2][8]=64 VGPR per half, same total ds_read/MFMA as R7, x-loads for
// half 1 are L1-hits. Live pressure ~115 < 128 -> no spill.

#define NROWS 131072
#define KD 256
#define ND 256
#define BM 256                      // rows per block
#define NBLK (NROWS / BM)           // 512

typedef __attribute__((ext_vector_type(8))) short short8;
typedef __attribute__((ext_vector_type(4))) float f32x4;
typedef __attribute__((ext_vector_type(4))) float flt4;

typedef __attribute__((address_space(3))) unsigned int lds_u32_t;
typedef __attribute__((address_space(1))) unsigned int glb_u32_t;

__device__ inline unsigned short f2bf(float f) {
    unsigned int u = __float_as_uint(f);
    u += 0x7FFFu + ((u >> 16) & 1u);   // RNE
    return (unsigned short)(u >> 16);
}

// ---- weight prep: wT[t][n][k] = bf16(w[t][k][n]) ----
__global__ __launch_bounds__(256) void prep_weights(const float* __restrict__ w,
                                                    unsigned short* __restrict__ wT) {
    __shared__ unsigned short L[8][264];
    const int t  = blockIdx.x >> 5;
    const int k0 = (blockIdx.x & 31) * 8;
    const int tid = threadIdx.x;

    #pragma unroll
    for (int i = 0; i < 2; ++i) {
        int idx = i * 256 + tid;
        int kr  = idx >> 6;
        int nq  = idx & 63;
        const flt4* src = (const flt4*)(w + ((size_t)t * 256 + k0 + kr) * 256);
        flt4 v = src[nq];
        #pragma unroll
        for (int j = 0; j < 4; ++j) L[kr][nq * 4 + j] = f2bf(v[j]);
    }
    __syncthreads();

    int n = tid;
    short8 v;
    #pragma unroll
    for (int j = 0; j < 8; ++j) v[j] = (short)L[j][n];
    *(short8*)(wT + ((size_t)t * 256 + n) * 256 + k0) = v;
}

// ---- main GEMM ----
__global__ __launch_bounds__(512) void hetero_gemm(
        const float* __restrict__ x, const int* __restrict__ tv,
        const unsigned short* __restrict__ wT, const float* __restrict__ bias,
        float* __restrict__ out) {
    // W[t] tile, bf16, [col][k], 512 B per col-row, XOR-swizzled 16B chunks:
    // LDS chunk c of col holds global k-chunk c ^ (col&7).
    __shared__ short Bs[BM * KD];            // 128 KiB

    const int tid  = threadIdx.x;
    const int lane = tid & 63;
    const int wv   = tid >> 6;               // 8 waves
    const int cl   = lane & 15;
    const int kg   = lane >> 4;
    const int r0   = blockIdx.x * BM;
    const int rw   = r0 + wv * 32;           // wave's 32-row strip

    const int tmin = tv[r0];
    const int tmax = tv[r0 + BM - 1];
    const int ty0  = tv[rw + cl];            // type of row (m=0)
    const int ty1  = tv[rw + 16 + cl];       // type of row (m=1)

    for (int t = tmin; t <= tmax; ++t) {
        if (t > tmin) __syncthreads();       // prev-pass reads done before overwrite

        // ---- stage W[t] -> LDS: 8192 16B chunks, 16 wave-rounds ----
        {
            const unsigned short* Wt = wT + (size_t)t * (KD * ND);
            #pragma unroll
            for (int rnd = 0; rnd < 16; ++rnd) {
                int i   = rnd * 512 + tid;   // chunk index 0..8191 (per-lane)
                int col = i >> 5;
                int c   = i & 31;
                int sc  = c ^ (col & 7);     // source-side swizzle
                const unsigned short* gp = Wt + col * KD + sc * 8;
                __builtin_amdgcn_global_load_lds(
                    (const glb_u32_t*)gp,
                    (lds_u32_t*)((char*)Bs + (size_t)(rnd * 512 + wv * 64) * 16),
                    16, 0, 0);
            }
        }
        __syncthreads();                     // drain DMA; tile ready

        const int s = cl & 7;                // swizzle key (col&7 == cl&7)

        // ---- compute in two col-halves: acc pressure 64 VGPR per half ----
        #pragma unroll
        for (int half = 0; half < 2; ++half) {
            const int c0 = half * 128;

            f32x4 zero = {0.f, 0.f, 0.f, 0.f};
            f32x4 acc[2][8];
            #pragma unroll
            for (int m = 0; m < 2; ++m)
                #pragma unroll
                for (int n = 0; n < 8; ++n) acc[m][n] = zero;

            short8 a_cur[2], a_nxt[2];
            #pragma unroll
            for (int m = 0; m < 2; ++m) {    // preload ks=0
                const float* ap = x + (size_t)(rw + m * 16 + cl) * KD + kg * 8;
                f32x4 v0 = *(const f32x4*)ap;
                f32x4 v1 = *(const f32x4*)(ap + 4);
                #pragma unroll
                for (int j = 0; j < 4; ++j) {
                    a_cur[m][j]     = (short)f2bf(v0[j]);
                    a_cur[m][4 + j] = (short)f2bf(v1[j]);
                }
            }

            #pragma unroll
            for (int ks = 0; ks < 8; ++ks) {
                if (ks < 7) {                // prefetch next k-slice of x
                    #pragma unroll
                    for (int m = 0; m < 2; ++m) {
                        const float* ap = x + (size_t)(rw + m * 16 + cl) * KD
                                            + (ks + 1) * 32 + kg * 8;
                        f32x4 v0 = *(const f32x4*)ap;
                        f32x4 v1 = *(const f32x4*)(ap + 4);
                        #pragma unroll
                        for (int j = 0; j < 4; ++j) {
                            a_nxt[m][j]     = (short)f2bf(v0[j]);
                            a_nxt[m][4 + j] = (short)f2bf(v1[j]);
                        }
                    }
                }
                #pragma unroll
                for (int n = 0; n < 8; ++n) {
                    int col = c0 + n * 16 + cl;
                    int kc  = ((ks << 2) | kg) ^ s;       // swizzled 16B chunk
                    short8 b = *(const short8*)((char*)Bs + (size_t)col * 512 + (kc << 4));
                    // swapped operands: D[w-col][x-row]
                    acc[0][n] = __builtin_amdgcn_mfma_f32_16x16x32_bf16(b, a_cur[0], acc[0][n], 0, 0, 0);
                    acc[1][n] = __builtin_amdgcn_mfma_f32_16x16x32_bf16(b, a_cur[1], acc[1][n], 0, 0, 0);
                }
                a_cur[0] = a_nxt[0];
                a_cur[1] = a_nxt[1];
            }

            // ---- epilogue for this half: rows rw+m*16+cl, cols c0+n*16+kg*4 ----
            #pragma unroll
            for (int m = 0; m < 2; ++m) {
                int tym = (m == 0) ? ty0 : ty1;
                if (tym == t) {
                    float* orow = out + (size_t)(rw + m * 16 + cl) * ND + c0 + kg * 4;
                    #pragma unroll
                    for (int n = 0; n < 8; ++n) {
                        f32x4 bv = *(const f32x4*)(bias + (size_t)t * ND + c0 + n * 16 + kg * 4);
                        f32x4 o  = acc[m][n] + bv;
                        __builtin_nontemporal_store(o, (f32x4*)(orow + n * 16));
                    }
                }
            }
        }
    }
}

extern "C" void kernel_launch(void* const* d_in, const int* in_sizes, int n_in,
                              void* d_out, int out_size, void* d_ws, size_t ws_size,
                              hipStream_t stream) {
    const float* x    = (const float*)d_in[0];
    const int*   tv   = (const int*)d_in[1];
    const float* w    = (const float*)d_in[2];
    const float* bias = (const float*)d_in[3];
    float* out = (float*)d_out;
    unsigned short* wT = (unsigned short*)d_ws;   // 8*256*256*2 = 1 MiB

    prep_weights<<<dim3(256), dim3(256), 0, stream>>>(w, wT);
    hetero_gemm<<<dim3(NBLK), dim3(512), 0, stream>>>(x, tv, wT, bias, out);
}